// Round 1
// baseline (792.883 us; speedup 1.0000x reference)
//
#include <hip/hip_runtime.h>
#include <stdint.h>

// Problem constants (B,T,C fixed by the reference)
#define Bn 8
#define Tn 2048
#define Cn 1024
#define Mn (Bn * Tn)     // 16384 flattened (b,t) rows
#define NTile (Tn / 64)  // 32 s-tiles per row

typedef __attribute__((ext_vector_type(4))) float f32x4;
typedef __attribute__((ext_vector_type(8))) short bf16x8;
typedef uint16_t u16;
typedef uint32_t u32;

static __device__ __forceinline__ u16 f2bf(float f) {
  union { float f; u32 u; } v; v.f = f;
  return (u16)((v.u + 0x7FFFu + ((v.u >> 16) & 1u)) >> 16);  // RNE
}
static __device__ __forceinline__ float bf2f(u16 h) {
  union { u32 u; float f; } v; v.u = ((u32)h) << 16;
  return v.f;
}
static __device__ __forceinline__ f32x4 mfma16(bf16x8 a, bf16x8 b, f32x4 c) {
  return __builtin_amdgcn_mfma_f32_16x16x32_bf16(a, b, c, 0, 0, 0);
}

struct Pack8 { uint4 hi, lo; };
// split 8 fp32 into bf16 hi + bf16 lo (residual): ~17-bit effective mantissa
static __device__ __forceinline__ Pack8 split8(float4 a, float4 b) {
  float f[8] = {a.x, a.y, a.z, a.w, b.x, b.y, b.z, b.w};
  union { u16 s[8]; uint4 v; } H, L;
#pragma unroll
  for (int j = 0; j < 8; ++j) {
    u16 h = f2bf(f[j]);
    H.s[j] = h;
    L.s[j] = f2bf(f[j] - bf2f(h));
  }
  Pack8 r; r.hi = H.v; r.lo = L.v; return r;
}

// ---------------------------------------------------------------------------
// K1: xH = x @ W^T, split-bf16 x3 MFMA for ~fp32 accuracy. 64x64 tile, BK=32.
// A = x [16384,1024] (row-major, k-contig), B = W [1024,1024] (B^T-natural).
// Epilogue stores xh as bf16 hi/lo pair.
// ---------------------------------------------------------------------------
__global__ __launch_bounds__(256) void k1_xh(const float* __restrict__ x,
                                             const float* __restrict__ W,
                                             u16* __restrict__ xh_hi,
                                             u16* __restrict__ xh_lo) {
  __shared__ __align__(16) u16 Ah[64 * 40], Al[64 * 40], Bh[64 * 40], Bl[64 * 40];
  const int tid = threadIdx.x;
  const int m0 = blockIdx.x * 64, n0 = blockIdx.y * 64;
  const int wave = tid >> 6, lane = tid & 63;
  const int wr = (wave >> 1) * 32, wc = (wave & 1) * 32;
  const int quad = lane >> 4, l16 = lane & 15;
  const int sr = tid >> 2, sc = (tid & 3) * 8;  // staging: row 0..63, col {0,8,16,24}

  f32x4 acc[2][2] = {{{0.f,0.f,0.f,0.f},{0.f,0.f,0.f,0.f}},
                     {{0.f,0.f,0.f,0.f},{0.f,0.f,0.f,0.f}}};

  const float* aB = x + (size_t)(m0 + sr) * Cn + sc;
  const float* bB = W + (size_t)(n0 + sr) * Cn + sc;

  for (int k0 = 0; k0 < Cn; k0 += 32) {
    Pack8 pa = split8(*(const float4*)(aB + k0), *(const float4*)(aB + k0 + 4));
    Pack8 pb = split8(*(const float4*)(bB + k0), *(const float4*)(bB + k0 + 4));
    *(uint4*)(Ah + sr * 40 + sc) = pa.hi;
    *(uint4*)(Al + sr * 40 + sc) = pa.lo;
    *(uint4*)(Bh + sr * 40 + sc) = pb.hi;
    *(uint4*)(Bl + sr * 40 + sc) = pb.lo;
    __syncthreads();
    bf16x8 a_h[2], a_l[2], b_h[2], b_l[2];
#pragma unroll
    for (int i = 0; i < 2; ++i) {
      a_h[i] = *(const bf16x8*)(Ah + (wr + i * 16 + l16) * 40 + quad * 8);
      a_l[i] = *(const bf16x8*)(Al + (wr + i * 16 + l16) * 40 + quad * 8);
      b_h[i] = *(const bf16x8*)(Bh + (wc + i * 16 + l16) * 40 + quad * 8);
      b_l[i] = *(const bf16x8*)(Bl + (wc + i * 16 + l16) * 40 + quad * 8);
    }
#pragma unroll
    for (int mi = 0; mi < 2; ++mi)
#pragma unroll
      for (int ni = 0; ni < 2; ++ni) {
        acc[mi][ni] = mfma16(a_h[mi], b_h[ni], acc[mi][ni]);
        acc[mi][ni] = mfma16(a_h[mi], b_l[ni], acc[mi][ni]);
        acc[mi][ni] = mfma16(a_l[mi], b_h[ni], acc[mi][ni]);
      }
    __syncthreads();
  }
#pragma unroll
  for (int mi = 0; mi < 2; ++mi)
#pragma unroll
    for (int ni = 0; ni < 2; ++ni)
#pragma unroll
      for (int r = 0; r < 4; ++r) {
        int row = wr + mi * 16 + quad * 4 + r;  // m (C/D: row = quad*4+reg)
        int col = wc + ni * 16 + l16;           // n (C/D: col = lane&15)
        float v = acc[mi][ni][r];
        size_t o = (size_t)(m0 + row) * Cn + n0 + col;
        u16 hh = f2bf(v);
        xh_hi[o] = hh;
        xh_lo[o] = f2bf(v - bf2f(hh));
      }
}

// ---------------------------------------------------------------------------
// K2: causal score tile S = x @ xH^T (split x3), lazy softmax:
// write P = exp(S - m_tile) bf16 (masked entries exactly 0), store m_t, l_t.
// Grid: x = triangular tile id (528), y = b.
// ---------------------------------------------------------------------------
__global__ __launch_bounds__(256) void k2_scores(const float* __restrict__ x,
                                                 const u16* __restrict__ xh_hi,
                                                 const u16* __restrict__ xh_lo,
                                                 u16* __restrict__ Pw,
                                                 float* __restrict__ mt,
                                                 float* __restrict__ lt) {
  __shared__ __align__(16) union {
    struct { u16 Ah[64 * 40], Al[64 * 40], Bh[64 * 40], Bl[64 * 40]; } c;
    struct { float S[64 * 68]; float m[64]; } e;
  } u;
  const int tid = threadIdx.x;
  const int b = blockIdx.y;
  int lin = blockIdx.x;
  int qt = 0;
  while ((qt + 1) * (qt + 2) / 2 <= lin) qt++;
  const int st = lin - qt * (qt + 1) / 2;
  const int t0 = qt * 64, s0 = st * 64;
  const int wave = tid >> 6, lane = tid & 63;
  const int wr = (wave >> 1) * 32, wc = (wave & 1) * 32;
  const int quad = lane >> 4, l16 = lane & 15;
  const int sr = tid >> 2, sc = (tid & 3) * 8;

  f32x4 acc[2][2] = {{{0.f,0.f,0.f,0.f},{0.f,0.f,0.f,0.f}},
                     {{0.f,0.f,0.f,0.f},{0.f,0.f,0.f,0.f}}};

  const float* aB = x + ((size_t)b * Tn + t0 + sr) * Cn + sc;
  const u16* bhB = xh_hi + ((size_t)b * Tn + s0 + sr) * Cn + sc;
  const u16* blB = xh_lo + ((size_t)b * Tn + s0 + sr) * Cn + sc;

  for (int k0 = 0; k0 < Cn; k0 += 32) {
    Pack8 pa = split8(*(const float4*)(aB + k0), *(const float4*)(aB + k0 + 4));
    uint4 vh = *(const uint4*)(bhB + k0);
    uint4 vl = *(const uint4*)(blB + k0);
    *(uint4*)(u.c.Ah + sr * 40 + sc) = pa.hi;
    *(uint4*)(u.c.Al + sr * 40 + sc) = pa.lo;
    *(uint4*)(u.c.Bh + sr * 40 + sc) = vh;
    *(uint4*)(u.c.Bl + sr * 40 + sc) = vl;
    __syncthreads();
    bf16x8 a_h[2], a_l[2], b_h[2], b_l[2];
#pragma unroll
    for (int i = 0; i < 2; ++i) {
      a_h[i] = *(const bf16x8*)(u.c.Ah + (wr + i * 16 + l16) * 40 + quad * 8);
      a_l[i] = *(const bf16x8*)(u.c.Al + (wr + i * 16 + l16) * 40 + quad * 8);
      b_h[i] = *(const bf16x8*)(u.c.Bh + (wc + i * 16 + l16) * 40 + quad * 8);
      b_l[i] = *(const bf16x8*)(u.c.Bl + (wc + i * 16 + l16) * 40 + quad * 8);
    }
#pragma unroll
    for (int mi = 0; mi < 2; ++mi)
#pragma unroll
      for (int ni = 0; ni < 2; ++ni) {
        acc[mi][ni] = mfma16(a_h[mi], b_h[ni], acc[mi][ni]);
        acc[mi][ni] = mfma16(a_h[mi], b_l[ni], acc[mi][ni]);
        acc[mi][ni] = mfma16(a_l[mi], b_h[ni], acc[mi][ni]);
      }
    __syncthreads();
  }

  // epilogue: masked scores -> LDS (reuses staging LDS; last barrier protects)
#pragma unroll
  for (int mi = 0; mi < 2; ++mi)
#pragma unroll
    for (int ni = 0; ni < 2; ++ni)
#pragma unroll
      for (int r = 0; r < 4; ++r) {
        int row = wr + mi * 16 + quad * 4 + r;
        int col = wc + ni * 16 + l16;
        int tg = t0 + row, sg = s0 + col;
        u.e.S[row * 68 + col] = (sg < tg) ? acc[mi][ni][r] : -1e30f;
      }
  __syncthreads();
  if (tid < 64) {
    float m = -1e30f;
    for (int i = 0; i < 64; ++i) m = fmaxf(m, u.e.S[tid * 68 + i]);
    float ls = 0.f;
    for (int i = 0; i < 64; ++i) ls += __expf(u.e.S[tid * 68 + i] - m);
    size_t rI = (size_t)b * Tn + t0 + tid;
    mt[rI * NTile + st] = m;  // all-masked row => m = -1e30 (only read when valid)
    lt[rI * NTile + st] = ls;
    u.e.m[tid] = m;
  }
  __syncthreads();
  {
    const int prow = tid >> 2;
    const int pg = (tid & 3) * 16;
    int tg = t0 + prow;
    float m = u.e.m[prow];
    union { u16 s[16]; uint4 v[2]; } pk;
#pragma unroll
    for (int j = 0; j < 16; ++j) {
      int col = pg + j;
      int sg = s0 + col;
      float val = u.e.S[prow * 68 + col];
      float p = (sg < tg) ? __expf(val - m) : 0.0f;  // explicit: masked -> exact 0
      pk.s[j] = f2bf(p);
    }
    u16* pb = Pw + ((size_t)b * Tn + tg) * Tn + s0 + pg;
    *(uint4*)(pb) = pk.v[0];
    *(uint4*)(pb + 8) = pk.v[1];
  }
}

// ---------------------------------------------------------------------------
// K3: per-row global max M and denom L from tile stats. Row t=0 -> L=0 -> Li=0.
// ---------------------------------------------------------------------------
__global__ __launch_bounds__(256) void k3_stats(const float* __restrict__ mt,
                                                const float* __restrict__ lt,
                                                float* __restrict__ Mr,
                                                float* __restrict__ Li) {
  int r = blockIdx.x * 256 + threadIdx.x;  // 0..16383
  int t = r & (Tn - 1);
  int nt = (t == 0) ? 0 : (((t - 1) >> 6) + 1);  // # causal s-tiles for this row
  float M = -1e30f;
  for (int i = 0; i < nt; ++i) M = fmaxf(M, mt[(size_t)r * NTile + i]);
  float L = 0.f;
  for (int i = 0; i < nt; ++i) L += lt[(size_t)r * NTile + i] * __expf(mt[(size_t)r * NTile + i] - M);
  Mr[r] = M;
  Li[r] = (L > 0.f) ? 1.f / L : 0.f;
}

// ---------------------------------------------------------------------------
// K3b: scale P in place: wei = P * exp(m_t - M) / L  (alpha in [0,1]).
// ---------------------------------------------------------------------------
__global__ __launch_bounds__(256) void k3b_scale(u16* __restrict__ P,
                                                 const float* __restrict__ mt,
                                                 const float* __restrict__ Mr,
                                                 const float* __restrict__ Li) {
  int lin = blockIdx.x, b = blockIdx.y;
  int qt = 0;
  while ((qt + 1) * (qt + 2) / 2 <= lin) qt++;
  int st = lin - qt * (qt + 1) / 2;
  int tid = threadIdx.x;
  int row = tid >> 2, g = (tid & 3) * 16;
  size_t r = (size_t)b * Tn + qt * 64 + row;
  float alpha = __expf(mt[r * NTile + st] - Mr[r]) * Li[r];
  u16* pb = P + r * Tn + st * 64 + g;
  union { u16 s[8]; uint4 v; } a0, a1;
  a0.v = *(uint4*)pb;
  a1.v = *(uint4*)(pb + 8);
#pragma unroll
  for (int j = 0; j < 8; ++j) { a0.s[j] = f2bf(bf2f(a0.s[j]) * alpha); a1.s[j] = f2bf(bf2f(a1.s[j]) * alpha); }
  *(uint4*)pb = a0.v;
  *(uint4*)(pb + 8) = a1.v;
}

// ---------------------------------------------------------------------------
// K4: out = -(P @ xH). A = P [t,s] k-contig; B = xH[s,c] transposed into LDS
// so the B fragment reads B[n=c][k=s] contiguously (ds_read_b128).
// ---------------------------------------------------------------------------
__global__ __launch_bounds__(256) void k4_out(const u16* __restrict__ P,
                                              const u16* __restrict__ xh_hi,
                                              float* __restrict__ out) {
  __shared__ __align__(16) u16 Ap[64 * 40];
  __shared__ __align__(16) u16 Bt[64 * 40];
  const int tid = threadIdx.x;
  const int qt = 31 - blockIdx.x;  // heavy tiles first
  const int cn = blockIdx.y, b = blockIdx.z;
  const int t0 = qt * 64, c0 = cn * 64;
  const int wave = tid >> 6, lane = tid & 63;
  const int wr = (wave >> 1) * 32, wc = (wave & 1) * 32;
  const int quad = lane >> 4, l16 = lane & 15;
  const int sr = tid >> 2, sc = (tid & 3) * 8;   // A staging: 64 x 32
  const int vs = tid >> 3, vc = (tid & 7) * 8;   // B staging: 32(s) x 64(c)

  f32x4 acc[2][2] = {{{0.f,0.f,0.f,0.f},{0.f,0.f,0.f,0.f}},
                     {{0.f,0.f,0.f,0.f},{0.f,0.f,0.f,0.f}}};

  const u16* aB = P + ((size_t)b * Tn + t0 + sr) * Tn + sc;
  const int kmax = (qt + 1) * 64;

  for (int ks = 0; ks < kmax; ks += 32) {
    uint4 av = *(const uint4*)(aB + ks);
    *(uint4*)(Ap + sr * 40 + sc) = av;
    union { uint4 v; u16 s[8]; } bv;
    bv.v = *(const uint4*)(xh_hi + ((size_t)b * Tn + ks + vs) * Cn + c0 + vc);
#pragma unroll
    for (int j = 0; j < 8; ++j) Bt[(vc + j) * 40 + vs] = bv.s[j];  // transpose write
    __syncthreads();
    bf16x8 a0 = *(const bf16x8*)(Ap + (wr + l16) * 40 + quad * 8);
    bf16x8 a1 = *(const bf16x8*)(Ap + (wr + 16 + l16) * 40 + quad * 8);
    bf16x8 b0 = *(const bf16x8*)(Bt + (wc + l16) * 40 + quad * 8);
    bf16x8 b1 = *(const bf16x8*)(Bt + (wc + 16 + l16) * 40 + quad * 8);
    acc[0][0] = mfma16(a0, b0, acc[0][0]);
    acc[0][1] = mfma16(a0, b1, acc[0][1]);
    acc[1][0] = mfma16(a1, b0, acc[1][0]);
    acc[1][1] = mfma16(a1, b1, acc[1][1]);
    __syncthreads();
  }
#pragma unroll
  for (int mi = 0; mi < 2; ++mi)
#pragma unroll
    for (int ni = 0; ni < 2; ++ni)
#pragma unroll
      for (int r = 0; r < 4; ++r) {
        int row = wr + mi * 16 + quad * 4 + r;
        int col = wc + ni * 16 + l16;
        out[((size_t)b * Tn + t0 + row) * Cn + c0 + col] = -acc[mi][ni][r];
      }
}

// ---------------------------------------------------------------------------
extern "C" void kernel_launch(void* const* d_in, const int* in_sizes, int n_in,
                              void* d_out, int out_size, void* d_ws, size_t ws_size,
                              hipStream_t stream) {
  (void)in_sizes; (void)n_in; (void)out_size; (void)ws_size;
  const float* x = (const float*)d_in[0];
  const float* W = (const float*)d_in[1];
  float* out = (float*)d_out;

  // workspace carve (total ~138.5 MB)
  char* ws = (char*)d_ws;
  u16* xh_hi = (u16*)ws; ws += (size_t)Mn * Cn * sizeof(u16);   // 33.55 MB
  u16* xh_lo = (u16*)ws; ws += (size_t)Mn * Cn * sizeof(u16);   // 33.55 MB
  u16* P     = (u16*)ws; ws += (size_t)Mn * Tn * sizeof(u16);   // 67.1 MB
  float* mt  = (float*)ws; ws += (size_t)Mn * NTile * sizeof(float);
  float* lt  = (float*)ws; ws += (size_t)Mn * NTile * sizeof(float);
  float* Mr  = (float*)ws; ws += (size_t)Mn * sizeof(float);
  float* Li  = (float*)ws; ws += (size_t)Mn * sizeof(float);

  dim3 blk(256);
  k1_xh<<<dim3(Mn / 64, Cn / 64), blk, 0, stream>>>(x, W, xh_hi, xh_lo);
  k2_scores<<<dim3(528, Bn), blk, 0, stream>>>(x, xh_hi, xh_lo, P, mt, lt);
  k3_stats<<<dim3(Mn / 256), blk, 0, stream>>>(mt, lt, Mr, Li);
  k3b_scale<<<dim3(528, Bn), blk, 0, stream>>>(P, mt, Mr, Li);
  k4_out<<<dim3(32, Cn / 64, Bn), blk, 0, stream>>>(P, xh_hi, out);
}

// Round 2
// 621.403 us; speedup vs baseline: 1.2760x; 1.2760x over previous
//
#include <hip/hip_runtime.h>
#include <stdint.h>

// Problem constants (B,T,C fixed by the reference)
#define Bn 8
#define Tn 2048
#define Cn 1024
#define BCH 4                 // batches per chunk (2 chunks)
#define Mc (BCH * Tn)         // 8192 rows per chunk
#define NT2 16                // s-tiles (128-wide) per row

typedef __attribute__((ext_vector_type(4))) float f32x4;
typedef __attribute__((ext_vector_type(8))) short bf16x8;
typedef uint16_t u16;
typedef uint32_t u32;

static __device__ __forceinline__ u16 f2bf(float f) {
  union { float f; u32 u; } v; v.f = f;
  return (u16)((v.u + 0x7FFFu + ((v.u >> 16) & 1u)) >> 16);  // RNE
}
static __device__ __forceinline__ float bf2f(u16 h) {
  union { u32 u; float f; } v; v.u = ((u32)h) << 16;
  return v.f;
}
static __device__ __forceinline__ f32x4 mfma16(bf16x8 a, bf16x8 b, f32x4 c) {
  return __builtin_amdgcn_mfma_f32_16x16x32_bf16(a, b, c, 0, 0, 0);
}
// async global->LDS, 16B per lane. LDS dest must be wave-uniform base + lane*16.
static __device__ __forceinline__ void gld16(const void* g, void* l) {
  __builtin_amdgcn_global_load_lds(
      (const __attribute__((address_space(1))) u32*)g,
      (__attribute__((address_space(3))) u32*)l, 16, 0, 0);
}

struct Pack8 { uint4 hi, lo; };
static __device__ __forceinline__ Pack8 split8(float4 a, float4 b) {
  float f[8] = {a.x, a.y, a.z, a.w, b.x, b.y, b.z, b.w};
  union { u16 s[8]; uint4 v; } H, L;
#pragma unroll
  for (int j = 0; j < 8; ++j) {
    u16 h = f2bf(f[j]);
    H.s[j] = h;
    L.s[j] = f2bf(f[j] - bf2f(h));
  }
  Pack8 r; r.hi = H.v; r.lo = L.v; return r;
}

// ---------------------------------------------------------------------------
// ksplit: fp32 -> bf16 hi/lo pair. Grid covers n/8 threads exactly.
// ---------------------------------------------------------------------------
__global__ __launch_bounds__(256) void ksplit(const float* __restrict__ s,
                                              u16* __restrict__ hi,
                                              u16* __restrict__ lo) {
  size_t i = ((size_t)blockIdx.x * 256 + threadIdx.x) * 8;
  Pack8 p = split8(*(const float4*)(s + i), *(const float4*)(s + i + 4));
  *(uint4*)(hi + i) = p.hi;
  *(uint4*)(lo + i) = p.lo;
}

// ---------------------------------------------------------------------------
// K1: xh = xs @ Ws^T (split-bf16 x3). 128x128 tile, BK=32, global_load_lds.
// ---------------------------------------------------------------------------
__global__ __launch_bounds__(256) void k1_xh(const u16* __restrict__ xs_hi,
                                             const u16* __restrict__ xs_lo,
                                             const u16* __restrict__ Ws_hi,
                                             const u16* __restrict__ Ws_lo,
                                             u16* __restrict__ xh_hi,
                                             u16* __restrict__ xh_lo) {
  __shared__ __align__(16) u16 Ah[128 * 32], Al[128 * 32], Bh[128 * 32], Bl[128 * 32];
  const int tid = threadIdx.x;
  const int m0 = blockIdx.x * 128, n0 = blockIdx.y * 128;
  const int wave = tid >> 6, lane = tid & 63;
  const int wrow = (wave >> 1) * 64, wcol = (wave & 1) * 64;
  const int quad = lane >> 4, l16 = lane & 15;
  const int srow = tid >> 2, skc = (tid & 3) * 8;

  f32x4 acc[4][4] = {};
  const size_t aoff = (size_t)(m0 + srow) * Cn + skc;
  const size_t boff = (size_t)(n0 + srow) * Cn + skc;

  for (int k0 = 0; k0 < Cn; k0 += 32) {
#pragma unroll
    for (int i = 0; i < 2; ++i) {
      size_t ro = (size_t)i * 64 * Cn;
      int lo_ = i * 2048 + tid * 8;
      gld16(xs_hi + aoff + ro + k0, Ah + lo_);
      gld16(xs_lo + aoff + ro + k0, Al + lo_);
      gld16(Ws_hi + boff + ro + k0, Bh + lo_);
      gld16(Ws_lo + boff + ro + k0, Bl + lo_);
    }
    __syncthreads();
    bf16x8 a_h[4], a_l[4], b_h[4], b_l[4];
#pragma unroll
    for (int i = 0; i < 4; ++i) {
      a_h[i] = *(const bf16x8*)(Ah + (wrow + i * 16 + l16) * 32 + quad * 8);
      a_l[i] = *(const bf16x8*)(Al + (wrow + i * 16 + l16) * 32 + quad * 8);
      b_h[i] = *(const bf16x8*)(Bh + (wcol + i * 16 + l16) * 32 + quad * 8);
      b_l[i] = *(const bf16x8*)(Bl + (wcol + i * 16 + l16) * 32 + quad * 8);
    }
#pragma unroll
    for (int mi = 0; mi < 4; ++mi)
#pragma unroll
      for (int ni = 0; ni < 4; ++ni) {
        acc[mi][ni] = mfma16(a_h[mi], b_h[ni], acc[mi][ni]);
        acc[mi][ni] = mfma16(a_h[mi], b_l[ni], acc[mi][ni]);
        acc[mi][ni] = mfma16(a_l[mi], b_h[ni], acc[mi][ni]);
      }
    __syncthreads();
  }
#pragma unroll
  for (int mi = 0; mi < 4; ++mi)
#pragma unroll
    for (int ni = 0; ni < 4; ++ni)
#pragma unroll
      for (int r = 0; r < 4; ++r) {
        int row = wrow + mi * 16 + quad * 4 + r;
        int col = wcol + ni * 16 + l16;
        float v = acc[mi][ni][r];
        size_t o = (size_t)(m0 + row) * Cn + n0 + col;
        u16 hh = f2bf(v);
        xh_hi[o] = hh;
        xh_lo[o] = f2bf(v - bf2f(hh));
      }
}

// ---------------------------------------------------------------------------
// K2: S = xs @ xh^T (split x3) on causal 128x128 tiles; lazy softmax epilogue:
// P = exp(S - m_tile) bf16 (masked -> exact 0), per-tile stats (m_t, l_t).
// ---------------------------------------------------------------------------
__global__ __launch_bounds__(256) void k2_scores(const u16* __restrict__ xs_hi,
                                                 const u16* __restrict__ xs_lo,
                                                 const u16* __restrict__ xh_hi,
                                                 const u16* __restrict__ xh_lo,
                                                 u16* __restrict__ P,
                                                 float* __restrict__ mt,
                                                 float* __restrict__ lt) {
  __shared__ __align__(16) union {
    struct { u16 Ah[4096], Al[4096], Bh[4096], Bl[4096]; } s;
    struct { float Mrow[2][128]; float Lrow[2][128]; } e;
  } u;
  const int tid = threadIdx.x;
  const int bL = blockIdx.y;
  int lin = blockIdx.x;
  int qt = 0;
  while ((qt + 1) * (qt + 2) / 2 <= lin) qt++;
  const int st = lin - qt * (qt + 1) / 2;
  const int t0 = qt * 128, s0 = st * 128;
  const int wave = tid >> 6, lane = tid & 63;
  const int wrow = (wave >> 1) * 64, wcol = (wave & 1) * 64;
  const int quad = lane >> 4, l16 = lane & 15;
  const int srow = tid >> 2, skc = (tid & 3) * 8;

  f32x4 acc[4][4] = {};
  const size_t aoff = ((size_t)bL * Tn + t0 + srow) * Cn + skc;
  const size_t boff = ((size_t)bL * Tn + s0 + srow) * Cn + skc;

  for (int k0 = 0; k0 < Cn; k0 += 32) {
#pragma unroll
    for (int i = 0; i < 2; ++i) {
      size_t ro = (size_t)i * 64 * Cn;
      int lo_ = i * 2048 + tid * 8;
      gld16(xs_hi + aoff + ro + k0, u.s.Ah + lo_);
      gld16(xs_lo + aoff + ro + k0, u.s.Al + lo_);
      gld16(xh_hi + boff + ro + k0, u.s.Bh + lo_);
      gld16(xh_lo + boff + ro + k0, u.s.Bl + lo_);
    }
    __syncthreads();
    bf16x8 a_h[4], a_l[4], b_h[4], b_l[4];
#pragma unroll
    for (int i = 0; i < 4; ++i) {
      a_h[i] = *(const bf16x8*)(u.s.Ah + (wrow + i * 16 + l16) * 32 + quad * 8);
      a_l[i] = *(const bf16x8*)(u.s.Al + (wrow + i * 16 + l16) * 32 + quad * 8);
      b_h[i] = *(const bf16x8*)(u.s.Bh + (wcol + i * 16 + l16) * 32 + quad * 8);
      b_l[i] = *(const bf16x8*)(u.s.Bl + (wcol + i * 16 + l16) * 32 + quad * 8);
    }
#pragma unroll
    for (int mi = 0; mi < 4; ++mi)
#pragma unroll
      for (int ni = 0; ni < 4; ++ni) {
        acc[mi][ni] = mfma16(a_h[mi], b_h[ni], acc[mi][ni]);
        acc[mi][ni] = mfma16(a_h[mi], b_l[ni], acc[mi][ni]);
        acc[mi][ni] = mfma16(a_l[mi], b_h[ni], acc[mi][ni]);
      }
    __syncthreads();
  }

  // ---- epilogue: mask, per-row max (shuffle + LDS combine), exp, stats, P ----
  float rm[4][4];
#pragma unroll
  for (int mi = 0; mi < 4; ++mi)
#pragma unroll
    for (int r = 0; r < 4; ++r) {
      int row = wrow + mi * 16 + quad * 4 + r;
      float m = -1e30f;
#pragma unroll
      for (int ni = 0; ni < 4; ++ni) {
        int col = wcol + ni * 16 + l16;
        if (s0 + col >= t0 + row) acc[mi][ni][r] = -1e30f;
        m = fmaxf(m, acc[mi][ni][r]);
      }
      m = fmaxf(m, __shfl_xor(m, 1));
      m = fmaxf(m, __shfl_xor(m, 2));
      m = fmaxf(m, __shfl_xor(m, 4));
      m = fmaxf(m, __shfl_xor(m, 8));
      rm[mi][r] = m;
    }
  if (l16 == 0) {
#pragma unroll
    for (int mi = 0; mi < 4; ++mi)
#pragma unroll
      for (int r = 0; r < 4; ++r)
        u.e.Mrow[wave & 1][wrow + mi * 16 + quad * 4 + r] = rm[mi][r];
  }
  __syncthreads();
  float rs[4][4];
#pragma unroll
  for (int mi = 0; mi < 4; ++mi)
#pragma unroll
    for (int r = 0; r < 4; ++r) {
      int row = wrow + mi * 16 + quad * 4 + r;
      float m2 = fmaxf(u.e.Mrow[0][row], u.e.Mrow[1][row]);
      float s = 0.f;
#pragma unroll
      for (int ni = 0; ni < 4; ++ni) {
        int col = wcol + ni * 16 + l16;
        float p = (s0 + col < t0 + row) ? __expf(acc[mi][ni][r] - m2) : 0.0f;
        acc[mi][ni][r] = p;
        s += p;
      }
      s += __shfl_xor(s, 1);
      s += __shfl_xor(s, 2);
      s += __shfl_xor(s, 4);
      s += __shfl_xor(s, 8);
      rs[mi][r] = s;
      rm[mi][r] = m2;
    }
  if (l16 == 0) {
#pragma unroll
    for (int mi = 0; mi < 4; ++mi)
#pragma unroll
      for (int r = 0; r < 4; ++r)
        u.e.Lrow[wave & 1][wrow + mi * 16 + quad * 4 + r] = rs[mi][r];
  }
  __syncthreads();
  if ((wave & 1) == 0 && l16 == 0) {
#pragma unroll
    for (int mi = 0; mi < 4; ++mi)
#pragma unroll
      for (int r = 0; r < 4; ++r) {
        int row = wrow + mi * 16 + quad * 4 + r;
        size_t rI = (size_t)bL * Tn + t0 + row;
        mt[rI * NT2 + st] = rm[mi][r];
        lt[rI * NT2 + st] = u.e.Lrow[0][row] + u.e.Lrow[1][row];
      }
  }
#pragma unroll
  for (int mi = 0; mi < 4; ++mi)
#pragma unroll
    for (int ni = 0; ni < 4; ++ni)
#pragma unroll
      for (int r = 0; r < 4; ++r) {
        int row = wrow + mi * 16 + quad * 4 + r;
        int col = wcol + ni * 16 + l16;
        P[((size_t)bL * Tn + t0 + row) * Tn + s0 + col] = f2bf(acc[mi][ni][r]);
      }
}

// ---------------------------------------------------------------------------
// K3: per-row global max M and inverse denom Li. Row t=0 -> Li=0.
// ---------------------------------------------------------------------------
__global__ __launch_bounds__(256) void k3_stats(const float* __restrict__ mt,
                                                const float* __restrict__ lt,
                                                float* __restrict__ Mr,
                                                float* __restrict__ Li) {
  int r = blockIdx.x * 256 + threadIdx.x;  // 0..Mc-1
  int t = r & (Tn - 1);
  int nt = (t == 0) ? 0 : (((t - 1) >> 7) + 1);
  float M = -1e30f;
  for (int i = 0; i < nt; ++i) M = fmaxf(M, mt[(size_t)r * NT2 + i]);
  float L = 0.f;
  for (int i = 0; i < nt; ++i) L += lt[(size_t)r * NT2 + i] * __expf(mt[(size_t)r * NT2 + i] - M);
  Mr[r] = M;
  Li[r] = (L > 0.f) ? 1.f / L : 0.f;
}

// ---------------------------------------------------------------------------
// K3b: P *= exp(m_t - M) / L  in place, per causal 128x128 tile.
// ---------------------------------------------------------------------------
__global__ __launch_bounds__(256) void k3b_scale(u16* __restrict__ P,
                                                 const float* __restrict__ mt,
                                                 const float* __restrict__ Mr,
                                                 const float* __restrict__ Li) {
  int lin = blockIdx.x, bL = blockIdx.y;
  int qt = 0;
  while ((qt + 1) * (qt + 2) / 2 <= lin) qt++;
  int st = lin - qt * (qt + 1) / 2;
  int row = threadIdx.x >> 1, half = (threadIdx.x & 1) * 64;
  size_t rI = (size_t)bL * Tn + qt * 128 + row;
  float alpha = __expf(mt[rI * NT2 + st] - Mr[rI]) * Li[rI];
  u16* pb = P + rI * Tn + st * 128 + half;
#pragma unroll
  for (int i = 0; i < 8; ++i) {
    union { u16 s[8]; uint4 v; } a;
    a.v = *(uint4*)(pb + i * 8);
#pragma unroll
    for (int j = 0; j < 8; ++j) a.s[j] = f2bf(bf2f(a.s[j]) * alpha);
    *(uint4*)(pb + i * 8) = a.v;
  }
}

// ---------------------------------------------------------------------------
// ktr: xhT[b][c][s] = xh_hi[b][s][c]  (128x128 LDS tiles)
// ---------------------------------------------------------------------------
__global__ __launch_bounds__(256) void ktr(const u16* __restrict__ src,
                                           u16* __restrict__ dst) {
  __shared__ __align__(16) u16 S[128 * 136];
  const int t0 = blockIdx.x * 128, c0 = blockIdx.y * 128, b = blockIdx.z;
  const int tid = threadIdx.x;
#pragma unroll
  for (int i = 0; i < 8; ++i) {
    int chunk = tid + i * 256;
    int row = chunk >> 4, c8 = (chunk & 15) * 8;
    uint4 v = *(const uint4*)(src + ((size_t)b * Tn + t0 + row) * Cn + c0 + c8);
    *(uint4*)(S + row * 136 + c8) = v;
  }
  __syncthreads();
#pragma unroll
  for (int i = 0; i < 8; ++i) {
    int chunk = tid + i * 256;
    int crow = chunk >> 4, t8 = (chunk & 15) * 8;
    union { u16 s[8]; uint4 v; } o;
#pragma unroll
    for (int j = 0; j < 8; ++j) o.s[j] = S[(t8 + j) * 136 + crow];
    *(uint4*)(dst + ((size_t)b * Cn + c0 + crow) * Tn + t0 + t8) = o.v;
  }
}

// ---------------------------------------------------------------------------
// K4: out = -(P @ xh). A = P (k-contig in s); B = xhT (k-contig in s).
// 128x128 tile, BK=32, global_load_lds both sides. Causal k range.
// ---------------------------------------------------------------------------
__global__ __launch_bounds__(256) void k4_out(const u16* __restrict__ P,
                                              const u16* __restrict__ xhT,
                                              float* __restrict__ out) {
  __shared__ __align__(16) u16 Ap[128 * 32], Bp[128 * 32];
  const int tid = threadIdx.x;
  const int tt = 15 - blockIdx.x;  // heavy tiles first
  const int cn = blockIdx.y, bL = blockIdx.z;
  const int t0 = tt * 128, c0 = cn * 128;
  const int wave = tid >> 6, lane = tid & 63;
  const int wrow = (wave >> 1) * 64, wcol = (wave & 1) * 64;
  const int quad = lane >> 4, l16 = lane & 15;
  const int srow = tid >> 2, skc = (tid & 3) * 8;

  f32x4 acc[4][4] = {};
  const size_t aoff = ((size_t)bL * Tn + t0 + srow) * Tn + skc;
  const size_t boff = ((size_t)bL * Cn + c0 + srow) * Tn + skc;
  const int kmax = (tt + 1) * 128;

  for (int k0 = 0; k0 < kmax; k0 += 32) {
#pragma unroll
    for (int i = 0; i < 2; ++i) {
      size_t ro = (size_t)i * 64 * Tn;
      int lo_ = i * 2048 + tid * 8;
      gld16(P + aoff + ro + k0, Ap + lo_);
      gld16(xhT + boff + ro + k0, Bp + lo_);
    }
    __syncthreads();
    bf16x8 a[4], b[4];
#pragma unroll
    for (int i = 0; i < 4; ++i) {
      a[i] = *(const bf16x8*)(Ap + (wrow + i * 16 + l16) * 32 + quad * 8);
      b[i] = *(const bf16x8*)(Bp + (wcol + i * 16 + l16) * 32 + quad * 8);
    }
#pragma unroll
    for (int mi = 0; mi < 4; ++mi)
#pragma unroll
      for (int ni = 0; ni < 4; ++ni)
        acc[mi][ni] = mfma16(a[mi], b[ni], acc[mi][ni]);
    __syncthreads();
  }
#pragma unroll
  for (int mi = 0; mi < 4; ++mi)
#pragma unroll
    for (int ni = 0; ni < 4; ++ni)
#pragma unroll
      for (int r = 0; r < 4; ++r) {
        int row = wrow + mi * 16 + quad * 4 + r;
        int col = wcol + ni * 16 + l16;
        out[((size_t)bL * Tn + t0 + row) * Cn + c0 + col] = -acc[mi][ni][r];
      }
}

// ---------------------------------------------------------------------------
extern "C" void kernel_launch(void* const* d_in, const int* in_sizes, int n_in,
                              void* d_out, int out_size, void* d_ws, size_t ws_size,
                              hipStream_t stream) {
  (void)in_sizes; (void)n_in; (void)out_size; (void)ws_size;
  const float* x = (const float*)d_in[0];
  const float* W = (const float*)d_in[1];
  float* out = (float*)d_out;

  // workspace carve — peak ~122.8 MB (chunked: 2 x 4 batches)
  char* ws = (char*)d_ws;
  u16* xs_hi = (u16*)ws; ws += (size_t)Mc * Cn * sizeof(u16);   // 16.78 MB
  u16* xs_lo = (u16*)ws; ws += (size_t)Mc * Cn * sizeof(u16);
  u16* xh_hi = (u16*)ws; ws += (size_t)Mc * Cn * sizeof(u16);
  u16* xh_lo = (u16*)ws; ws += (size_t)Mc * Cn * sizeof(u16);
  u16* P     = (u16*)ws; ws += (size_t)Mc * Tn * sizeof(u16);   // 33.55 MB
  u16* xhT   = (u16*)ws; ws += (size_t)BCH * Cn * Tn * sizeof(u16); // 16.78 MB
  u16* Ws_hi = (u16*)ws; ws += (size_t)Cn * Cn * sizeof(u16);   // 2.1 MB
  u16* Ws_lo = (u16*)ws; ws += (size_t)Cn * Cn * sizeof(u16);
  float* mt  = (float*)ws; ws += (size_t)Mc * NT2 * sizeof(float);
  float* lt  = (float*)ws; ws += (size_t)Mc * NT2 * sizeof(float);
  float* Mr  = (float*)ws; ws += (size_t)Mc * sizeof(float);
  float* Li  = (float*)ws; ws += (size_t)Mc * sizeof(float);

  dim3 blk(256);
  ksplit<<<dim3(Cn * Cn / 8 / 256), blk, 0, stream>>>(W, Ws_hi, Ws_lo);
  for (int c = 0; c < 2; ++c) {
    const float* xc = x + (size_t)c * BCH * Tn * Cn;
    float* oc = out + (size_t)c * BCH * Tn * Cn;
    ksplit<<<dim3((size_t)Mc * Cn / 8 / 256), blk, 0, stream>>>(xc, xs_hi, xs_lo);
    k1_xh<<<dim3(Mc / 128, Cn / 128), blk, 0, stream>>>(xs_hi, xs_lo, Ws_hi, Ws_lo, xh_hi, xh_lo);
    k2_scores<<<dim3(136, BCH), blk, 0, stream>>>(xs_hi, xs_lo, xh_hi, xh_lo, P, mt, lt);
    k3_stats<<<dim3(Mc / 256), blk, 0, stream>>>(mt, lt, Mr, Li);
    k3b_scale<<<dim3(136, BCH), blk, 0, stream>>>(P, mt, Mr, Li);
    ktr<<<dim3(Tn / 128, Cn / 128, BCH), blk, 0, stream>>>(xh_hi, xhT);
    k4_out<<<dim3(Tn / 128, Cn / 128, BCH), blk, 0, stream>>>(P, xhT, oc);
  }
}

// Round 3
// 459.684 us; speedup vs baseline: 1.7248x; 1.3518x over previous
//
#include <hip/hip_runtime.h>
#include <stdint.h>

// Problem constants
#define Bn 8
#define Tn 2048
#define Cn 1024
#define Mn (Bn * Tn)
#define NTRI 136   // causal 128x128 tiles per batch: 16*17/2

typedef __attribute__((ext_vector_type(4))) float f32x4;
typedef _Float16 f16;
typedef __attribute__((ext_vector_type(8))) _Float16 f16x8;
typedef uint16_t u16;
typedef uint32_t u32;

static __device__ __forceinline__ u16 f2h(float f) {
  union { f16 h; u16 u; } c; c.h = (f16)f; return c.u;
}
static __device__ __forceinline__ f32x4 mfmaH(f16x8 a, f16x8 b, f32x4 c) {
  return __builtin_amdgcn_mfma_f32_16x16x32_f16(a, b, c, 0, 0, 0);
}
// async global->LDS, 16B/lane; LDS dest = wave-uniform base + lane*16.
static __device__ __forceinline__ void gld16(const void* g, void* l) {
  __builtin_amdgcn_global_load_lds(
      (const __attribute__((address_space(1))) u32*)g,
      (__attribute__((address_space(3))) u32*)l, 16, 0, 0);
}

// ---------------------------------------------------------------------------
// ksplitW: W fp32 -> fp16 hi only.
// ---------------------------------------------------------------------------
__global__ __launch_bounds__(256) void ksplitW(const float* __restrict__ s,
                                               u16* __restrict__ hi) {
  size_t i = ((size_t)blockIdx.x * 256 + threadIdx.x) * 8;
  float4 a = *(const float4*)(s + i), b = *(const float4*)(s + i + 4);
  float f[8] = {a.x, a.y, a.z, a.w, b.x, b.y, b.z, b.w};
  union { u16 u[8]; uint4 v; } H;
#pragma unroll
  for (int j = 0; j < 8; ++j) H.u[j] = f2h(f[j]);
  *(uint4*)(hi + i) = H.v;
}

// ---------------------------------------------------------------------------
// ksplitX: x fp32 -> fp16 hi + fp16 lo residual (~22-bit effective).
// ---------------------------------------------------------------------------
__global__ __launch_bounds__(256) void ksplitX(const float* __restrict__ s,
                                               u16* __restrict__ hi,
                                               u16* __restrict__ lo) {
  size_t i = ((size_t)blockIdx.x * 256 + threadIdx.x) * 8;
  float4 a = *(const float4*)(s + i), b = *(const float4*)(s + i + 4);
  float f[8] = {a.x, a.y, a.z, a.w, b.x, b.y, b.z, b.w};
  union { u16 u[8]; uint4 v; } H, L;
#pragma unroll
  for (int j = 0; j < 8; ++j) {
    f16 h = (f16)f[j];
    union { f16 h; u16 u; } ch; ch.h = h;
    H.u[j] = ch.u;
    L.u[j] = f2h(f[j] - (float)h);
  }
  *(uint4*)(hi + i) = H.v;
  *(uint4*)(lo + i) = L.v;
}

// ---------------------------------------------------------------------------
// K1: xh = (x_h + x_l) @ W_h^T  (2 fp16 MFMA terms). 128x128 tile, BK=32.
// ---------------------------------------------------------------------------
__global__ __launch_bounds__(256) void k1_xh(const u16* __restrict__ x_h,
                                             const u16* __restrict__ x_l,
                                             const u16* __restrict__ W_h,
                                             u16* __restrict__ xh) {
  __shared__ __align__(16) u16 Ah[4096], Al[4096], Bh[4096];
  const int tid = threadIdx.x;
  const int m0 = blockIdx.x * 128, n0 = blockIdx.y * 128;
  const int wave = tid >> 6, lane = tid & 63;
  const int wrow = (wave >> 1) * 64, wcol = (wave & 1) * 64;
  const int quad = lane >> 4, l16 = lane & 15;
  const int srow = tid >> 2, skc = (tid & 3) * 8;

  f32x4 acc[4][4] = {};
  const size_t aoff = (size_t)(m0 + srow) * Cn + skc;
  const size_t boff = (size_t)(n0 + srow) * Cn + skc;

  for (int k0 = 0; k0 < Cn; k0 += 32) {
#pragma unroll
    for (int i = 0; i < 2; ++i) {
      size_t ro = (size_t)i * 64 * Cn;
      int lo_ = i * 2048 + tid * 8;
      gld16(x_h + aoff + ro + k0, Ah + lo_);
      gld16(x_l + aoff + ro + k0, Al + lo_);
      gld16(W_h + boff + ro + k0, Bh + lo_);
    }
    __syncthreads();
    f16x8 a_h[4], a_l[4], b_h[4];
#pragma unroll
    for (int i = 0; i < 4; ++i) {
      a_h[i] = *(const f16x8*)(Ah + (wrow + i * 16 + l16) * 32 + quad * 8);
      a_l[i] = *(const f16x8*)(Al + (wrow + i * 16 + l16) * 32 + quad * 8);
      b_h[i] = *(const f16x8*)(Bh + (wcol + i * 16 + l16) * 32 + quad * 8);
    }
#pragma unroll
    for (int mi = 0; mi < 4; ++mi)
#pragma unroll
      for (int ni = 0; ni < 4; ++ni) {
        acc[mi][ni] = mfmaH(a_h[mi], b_h[ni], acc[mi][ni]);
        acc[mi][ni] = mfmaH(a_l[mi], b_h[ni], acc[mi][ni]);
      }
    __syncthreads();
  }
#pragma unroll
  for (int mi = 0; mi < 4; ++mi)
#pragma unroll
    for (int ni = 0; ni < 4; ++ni)
#pragma unroll
      for (int r = 0; r < 4; ++r) {
        int row = wrow + mi * 16 + quad * 4 + r;
        int col = wcol + ni * 16 + l16;
        xh[(size_t)(m0 + row) * Cn + n0 + col] = f2h(acc[mi][ni][r]);
      }
}

// ---------------------------------------------------------------------------
// K2: S = (x_h + x_l) @ xh^T (2 terms) on causal 128x128 tiles; lazy softmax:
// P = exp(S - m_tile) fp16 into PACKED triangular tile storage; stats (m,l).
// ---------------------------------------------------------------------------
__global__ __launch_bounds__(256) void k2_scores(const u16* __restrict__ x_h,
                                                 const u16* __restrict__ x_l,
                                                 const u16* __restrict__ xh,
                                                 u16* __restrict__ P,
                                                 float* __restrict__ mt,
                                                 float* __restrict__ lt) {
  __shared__ __align__(16) union {
    struct { u16 Ah[4096], Al[4096], Bh[4096]; } s;
    struct { float Mrow[2][128]; float Lrow[2][128]; } e;
  } u;
  const int tid = threadIdx.x;
  const int bL = blockIdx.y;
  const int lin = blockIdx.x;
  int qt = 0;
  while ((qt + 1) * (qt + 2) / 2 <= lin) qt++;
  const int st = lin - qt * (qt + 1) / 2;
  const int t0 = qt * 128, s0 = st * 128;
  const int wave = tid >> 6, lane = tid & 63;
  const int wrow = (wave >> 1) * 64, wcol = (wave & 1) * 64;
  const int quad = lane >> 4, l16 = lane & 15;
  const int srow = tid >> 2, skc = (tid & 3) * 8;

  f32x4 acc[4][4] = {};
  const size_t aoff = ((size_t)bL * Tn + t0 + srow) * Cn + skc;
  const size_t boff = ((size_t)bL * Tn + s0 + srow) * Cn + skc;

  for (int k0 = 0; k0 < Cn; k0 += 32) {
#pragma unroll
    for (int i = 0; i < 2; ++i) {
      size_t ro = (size_t)i * 64 * Cn;
      int lo_ = i * 2048 + tid * 8;
      gld16(x_h + aoff + ro + k0, u.s.Ah + lo_);
      gld16(x_l + aoff + ro + k0, u.s.Al + lo_);
      gld16(xh + boff + ro + k0, u.s.Bh + lo_);
    }
    __syncthreads();
    f16x8 a_h[4], a_l[4], b_h[4];
#pragma unroll
    for (int i = 0; i < 4; ++i) {
      a_h[i] = *(const f16x8*)(u.s.Ah + (wrow + i * 16 + l16) * 32 + quad * 8);
      a_l[i] = *(const f16x8*)(u.s.Al + (wrow + i * 16 + l16) * 32 + quad * 8);
      b_h[i] = *(const f16x8*)(u.s.Bh + (wcol + i * 16 + l16) * 32 + quad * 8);
    }
#pragma unroll
    for (int mi = 0; mi < 4; ++mi)
#pragma unroll
      for (int ni = 0; ni < 4; ++ni) {
        acc[mi][ni] = mfmaH(a_h[mi], b_h[ni], acc[mi][ni]);
        acc[mi][ni] = mfmaH(a_l[mi], b_h[ni], acc[mi][ni]);
      }
    __syncthreads();
  }

  // ---- epilogue: mask, per-row max, exp, stats, packed-P write ----
  float rm[4][4];
#pragma unroll
  for (int mi = 0; mi < 4; ++mi)
#pragma unroll
    for (int r = 0; r < 4; ++r) {
      int row = wrow + mi * 16 + quad * 4 + r;
      float m = -1e30f;
#pragma unroll
      for (int ni = 0; ni < 4; ++ni) {
        int col = wcol + ni * 16 + l16;
        if (s0 + col >= t0 + row) acc[mi][ni][r] = -1e30f;
        m = fmaxf(m, acc[mi][ni][r]);
      }
      m = fmaxf(m, __shfl_xor(m, 1));
      m = fmaxf(m, __shfl_xor(m, 2));
      m = fmaxf(m, __shfl_xor(m, 4));
      m = fmaxf(m, __shfl_xor(m, 8));
      rm[mi][r] = m;
    }
  if (l16 == 0) {
#pragma unroll
    for (int mi = 0; mi < 4; ++mi)
#pragma unroll
      for (int r = 0; r < 4; ++r)
        u.e.Mrow[wave & 1][wrow + mi * 16 + quad * 4 + r] = rm[mi][r];
  }
  __syncthreads();
  float rs[4][4];
#pragma unroll
  for (int mi = 0; mi < 4; ++mi)
#pragma unroll
    for (int r = 0; r < 4; ++r) {
      int row = wrow + mi * 16 + quad * 4 + r;
      float m2 = fmaxf(u.e.Mrow[0][row], u.e.Mrow[1][row]);
      float s = 0.f;
#pragma unroll
      for (int ni = 0; ni < 4; ++ni) {
        int col = wcol + ni * 16 + l16;
        float p = (s0 + col < t0 + row) ? __expf(acc[mi][ni][r] - m2) : 0.0f;
        acc[mi][ni][r] = p;
        s += p;
      }
      s += __shfl_xor(s, 1);
      s += __shfl_xor(s, 2);
      s += __shfl_xor(s, 4);
      s += __shfl_xor(s, 8);
      rs[mi][r] = s;
      rm[mi][r] = m2;
    }
  if (l16 == 0) {
#pragma unroll
    for (int mi = 0; mi < 4; ++mi)
#pragma unroll
      for (int r = 0; r < 4; ++r)
        u.e.Lrow[wave & 1][wrow + mi * 16 + quad * 4 + r] = rs[mi][r];
  }
  __syncthreads();
  if ((wave & 1) == 0 && l16 == 0) {
#pragma unroll
    for (int mi = 0; mi < 4; ++mi)
#pragma unroll
      for (int r = 0; r < 4; ++r) {
        int row = wrow + mi * 16 + quad * 4 + r;
        size_t rI = (size_t)bL * Tn + t0 + row;
        mt[rI * 16 + st] = rm[mi][r];
        lt[rI * 16 + st] = u.e.Lrow[0][row] + u.e.Lrow[1][row];
      }
  }
  const size_t pbase = (size_t)(bL * NTRI + lin) * 16384;
#pragma unroll
  for (int mi = 0; mi < 4; ++mi)
#pragma unroll
    for (int ni = 0; ni < 4; ++ni)
#pragma unroll
      for (int r = 0; r < 4; ++r) {
        int row = wrow + mi * 16 + quad * 4 + r;
        int col = wcol + ni * 16 + l16;
        P[pbase + row * 128 + col] = f2h(acc[mi][ni][r]);
      }
}

// ---------------------------------------------------------------------------
// K3: per-row global max M and inverse denom Li. Row t=0 -> Li=0.
// ---------------------------------------------------------------------------
__global__ __launch_bounds__(256) void k3_stats(const float* __restrict__ mt,
                                                const float* __restrict__ lt,
                                                float* __restrict__ Mr,
                                                float* __restrict__ Li) {
  int r = blockIdx.x * 256 + threadIdx.x;
  int t = r & (Tn - 1);
  int nt = (t == 0) ? 0 : (((t - 1) >> 7) + 1);
  float M = -1e30f;
  for (int i = 0; i < nt; ++i) M = fmaxf(M, mt[(size_t)r * 16 + i]);
  float L = 0.f;
  for (int i = 0; i < nt; ++i) L += lt[(size_t)r * 16 + i] * __expf(mt[(size_t)r * 16 + i] - M);
  Mr[r] = M;
  Li[r] = (L > 0.f) ? 1.f / L : 0.f;
}

// ---------------------------------------------------------------------------
// ktr: xhT[b][c][s] = xh[b][s][c]  (fp16, 128x128 LDS tiles)
// ---------------------------------------------------------------------------
__global__ __launch_bounds__(256) void ktr(const u16* __restrict__ src,
                                           u16* __restrict__ dst) {
  __shared__ __align__(16) u16 S[128 * 136];
  const int t0 = blockIdx.x * 128, c0 = blockIdx.y * 128, b = blockIdx.z;
  const int tid = threadIdx.x;
#pragma unroll
  for (int i = 0; i < 8; ++i) {
    int chunk = tid + i * 256;
    int row = chunk >> 4, c8 = (chunk & 15) * 8;
    uint4 v = *(const uint4*)(src + ((size_t)b * Tn + t0 + row) * Cn + c0 + c8);
    *(uint4*)(S + row * 136 + c8) = v;
  }
  __syncthreads();
#pragma unroll
  for (int i = 0; i < 8; ++i) {
    int chunk = tid + i * 256;
    int crow = chunk >> 4, t8 = (chunk & 15) * 8;
    union { u16 s[8]; uint4 v; } o;
#pragma unroll
    for (int j = 0; j < 8; ++j) o.s[j] = S[(t8 + j) * 136 + crow];
    *(uint4*)(dst + ((size_t)b * Cn + c0 + crow) * Tn + t0 + t8) = o.v;
  }
}

// ---------------------------------------------------------------------------
// K4: out = -( (P*alpha) @ xh ), alpha(row,st) = exp(m_t - M) / L folded into
// the A fragment (v_pk_mul_f16). A = packed P tiles; B = xhT (k=s contig).
// ---------------------------------------------------------------------------
__global__ __launch_bounds__(256) void k4_out(const u16* __restrict__ P,
                                              const u16* __restrict__ xhT,
                                              const float* __restrict__ mt,
                                              const float* __restrict__ Mr,
                                              const float* __restrict__ Li,
                                              float* __restrict__ out) {
  __shared__ __align__(16) u16 Ap[4096], Bp[4096];
  const int tid = threadIdx.x;
  const int tt = 15 - blockIdx.x;  // heavy tiles first
  const int cn = blockIdx.y, bL = blockIdx.z;
  const int t0 = tt * 128, c0 = cn * 128;
  const int wave = tid >> 6, lane = tid & 63;
  const int wrow = (wave >> 1) * 64, wcol = (wave & 1) * 64;
  const int quad = lane >> 4, l16 = lane & 15;
  const int srow = tid >> 2, skc = (tid & 3) * 8;

  f32x4 acc[4][4] = {};
  size_t rI[4]; float MrL[4], LiL[4];
#pragma unroll
  for (int mi = 0; mi < 4; ++mi) {
    rI[mi] = (size_t)bL * Tn + t0 + wrow + mi * 16 + l16;
    MrL[mi] = Mr[rI[mi]];
    LiL[mi] = Li[rI[mi]];
  }
  const size_t bbase = ((size_t)bL * Cn + c0) * Tn;

  for (int st = 0; st <= tt; ++st) {
    f16 ah[4];
#pragma unroll
    for (int mi = 0; mi < 4; ++mi)
      ah[mi] = (f16)(__expf(mt[rI[mi] * 16 + st] - MrL[mi]) * LiL[mi]);
    const size_t pbase = (size_t)(bL * NTRI + tt * (tt + 1) / 2 + st) * 16384;
    for (int kl = 0; kl < 128; kl += 32) {
#pragma unroll
      for (int i = 0; i < 2; ++i) {
        int lo_ = i * 2048 + tid * 8;
        gld16(P + pbase + (size_t)(i * 64 + srow) * 128 + kl + skc, Ap + lo_);
        gld16(xhT + bbase + (size_t)(i * 64 + srow) * Tn + st * 128 + kl + skc, Bp + lo_);
      }
      __syncthreads();
      f16x8 a[4], b[4];
#pragma unroll
      for (int i = 0; i < 4; ++i) {
        a[i] = *(const f16x8*)(Ap + (wrow + i * 16 + l16) * 32 + quad * 8);
        f16x8 sv;
#pragma unroll
        for (int j = 0; j < 8; ++j) sv[j] = ah[i];
        a[i] = a[i] * sv;
        b[i] = *(const f16x8*)(Bp + (wcol + i * 16 + l16) * 32 + quad * 8);
      }
#pragma unroll
      for (int mi = 0; mi < 4; ++mi)
#pragma unroll
        for (int ni = 0; ni < 4; ++ni)
          acc[mi][ni] = mfmaH(a[mi], b[ni], acc[mi][ni]);
      __syncthreads();
    }
  }
#pragma unroll
  for (int mi = 0; mi < 4; ++mi)
#pragma unroll
    for (int ni = 0; ni < 4; ++ni)
#pragma unroll
      for (int r = 0; r < 4; ++r) {
        int row = wrow + mi * 16 + quad * 4 + r;
        int col = wcol + ni * 16 + l16;
        out[((size_t)bL * Tn + t0 + row) * Cn + c0 + col] = -acc[mi][ni][r];
      }
}

// ---------------------------------------------------------------------------
extern "C" void kernel_launch(void* const* d_in, const int* in_sizes, int n_in,
                              void* d_out, int out_size, void* d_ws, size_t ws_size,
                              hipStream_t stream) {
  (void)in_sizes; (void)n_in; (void)out_size;
  const float* x = (const float*)d_in[0];
  const float* W = (const float*)d_in[1];
  float* out = (float*)d_out;

  // full-batch path needs ~140.6 MB; else fall back to 2 chunks (~71 MB)
  const size_t FULL_NEED = 3ull * Mn * Cn * 2 + (size_t)Bn * NTRI * 16384 * 2 +
                           (size_t)Cn * Cn * 2 + 2ull * Mn * 16 * 4 + 2ull * Mn * 4;
  const int nch = (ws_size >= FULL_NEED) ? 1 : 2;
  const int nb = Bn / nch;
  const size_t rowsC = (size_t)nb * Tn;       // rows per pass
  const size_t sA = rowsC * Cn * 2;           // fp16 plane bytes

  char* p = (char*)d_ws;
  u16* x_h = (u16*)p; p += sA;
  u16* xLT = (u16*)p; p += sA;                // x_l, later reused as xhT
  u16* xh  = (u16*)p; p += sA;
  u16* Pp  = (u16*)p; p += (size_t)nb * NTRI * 16384 * 2;
  u16* W_h = (u16*)p; p += (size_t)Cn * Cn * 2;
  float* mt = (float*)p; p += rowsC * 16 * 4;
  float* lt = (float*)p; p += rowsC * 16 * 4;
  float* Mr = (float*)p; p += rowsC * 4;
  float* Li = (float*)p; p += rowsC * 4;

  dim3 blk(256);
  ksplitW<<<dim3(Cn * Cn / 2048), blk, 0, stream>>>(W, W_h);
  for (int c = 0; c < nch; ++c) {
    const float* xc = x + (size_t)c * rowsC * Cn;
    float* oc = out + (size_t)c * rowsC * Cn;
    ksplitX<<<dim3((u32)(rowsC * Cn / 2048)), blk, 0, stream>>>(xc, x_h, xLT);
    k1_xh<<<dim3((u32)(rowsC / 128), Cn / 128), blk, 0, stream>>>(x_h, xLT, W_h, xh);
    k2_scores<<<dim3(NTRI, nb), blk, 0, stream>>>(x_h, xLT, xh, Pp, mt, lt);
    k3_stats<<<dim3((u32)(rowsC / 256)), blk, 0, stream>>>(mt, lt, Mr, Li);
    ktr<<<dim3(Tn / 128, Cn / 128, nb), blk, 0, stream>>>(xh, xLT);
    k4_out<<<dim3(16, Cn / 128, nb), blk, 0, stream>>>(Pp, xLT, mt, Mr, Li, oc);
  }
}

// Round 4
// 427.061 us; speedup vs baseline: 1.8566x; 1.0764x over previous
//
#include <hip/hip_runtime.h>
#include <stdint.h>

// Problem constants
#define Bn 8
#define Tn 2048
#define Cn 1024
#define Mn (Bn * Tn)
#define NTRI 136   // causal 128x128 tiles per batch: 16*17/2

typedef __attribute__((ext_vector_type(4))) float f32x4;
typedef _Float16 f16;
typedef __attribute__((ext_vector_type(8))) _Float16 f16x8;
typedef uint16_t u16;
typedef uint32_t u32;

static __device__ __forceinline__ u16 f2h(float f) {
  union { f16 h; u16 u; } c; c.h = (f16)f; return c.u;
}
static __device__ __forceinline__ f32x4 mfmaH(f16x8 a, f16x8 b, f32x4 c) {
  return __builtin_amdgcn_mfma_f32_16x16x32_f16(a, b, c, 0, 0, 0);
}
// async global->LDS, 16B/lane; LDS dest = wave-uniform base + lane*16.
static __device__ __forceinline__ void gld16(const void* g, void* l) {
  __builtin_amdgcn_global_load_lds(
      (const __attribute__((address_space(1))) u32*)g,
      (__attribute__((address_space(3))) u32*)l, 16, 0, 0);
}

// ---------------------------------------------------------------------------
// ksplitW: W fp32 -> fp16 hi only.
// ---------------------------------------------------------------------------
__global__ __launch_bounds__(256) void ksplitW(const float* __restrict__ s,
                                               u16* __restrict__ hi) {
  size_t i = ((size_t)blockIdx.x * 256 + threadIdx.x) * 8;
  float4 a = *(const float4*)(s + i), b = *(const float4*)(s + i + 4);
  float f[8] = {a.x, a.y, a.z, a.w, b.x, b.y, b.z, b.w};
  union { u16 u[8]; uint4 v; } H;
#pragma unroll
  for (int j = 0; j < 8; ++j) H.u[j] = f2h(f[j]);
  *(uint4*)(hi + i) = H.v;
}

// ---------------------------------------------------------------------------
// ksplitX: x fp32 -> fp16 hi + fp16 lo residual (~22-bit effective).
// ---------------------------------------------------------------------------
__global__ __launch_bounds__(256) void ksplitX(const float* __restrict__ s,
                                               u16* __restrict__ hi,
                                               u16* __restrict__ lo) {
  size_t i = ((size_t)blockIdx.x * 256 + threadIdx.x) * 8;
  float4 a = *(const float4*)(s + i), b = *(const float4*)(s + i + 4);
  float f[8] = {a.x, a.y, a.z, a.w, b.x, b.y, b.z, b.w};
  union { u16 u[8]; uint4 v; } H, L;
#pragma unroll
  for (int j = 0; j < 8; ++j) {
    f16 h = (f16)f[j];
    union { f16 h; u16 u; } ch; ch.h = h;
    H.u[j] = ch.u;
    L.u[j] = f2h(f[j] - (float)h);
  }
  *(uint4*)(hi + i) = H.v;
  *(uint4*)(lo + i) = L.v;
}

// ---------------------------------------------------------------------------
// K1: xh = x_h @ W_h^T  (1 fp16 MFMA term; x_l term dropped — its error
// (~2.2e-4) is below xh's own fp16 quantization). 128x128 tile, BK=64 as two
// [128][32] half-buffers (bank-identical to the proven BK=32 layout).
// ---------------------------------------------------------------------------
__global__ __launch_bounds__(256) void k1_xh(const u16* __restrict__ x_h,
                                             const u16* __restrict__ W_h,
                                             u16* __restrict__ xh) {
  __shared__ __align__(16) u16 Ah[8192], Bh[8192];
  const int tid = threadIdx.x;
  const int m0 = blockIdx.x * 128, n0 = blockIdx.y * 128;
  const int wave = tid >> 6, lane = tid & 63;
  const int wrow = (wave >> 1) * 64, wcol = (wave & 1) * 64;
  const int quad = lane >> 4, l16 = lane & 15;

  f32x4 acc[4][4] = {};

  for (int k0 = 0; k0 < Cn; k0 += 64) {
#pragma unroll
    for (int i = 0; i < 4; ++i) {
      int chunk = i * 256 + tid;
      int kk = chunk >> 9, row = (chunk >> 2) & 127, c8 = (chunk & 3) * 8;
      gld16(x_h + (size_t)(m0 + row) * Cn + k0 + kk * 32 + c8, Ah + chunk * 8);
      gld16(W_h + (size_t)(n0 + row) * Cn + k0 + kk * 32 + c8, Bh + chunk * 8);
    }
    __syncthreads();
#pragma unroll
    for (int kk = 0; kk < 2; ++kk) {
      f16x8 a[4], b[4];
#pragma unroll
      for (int i = 0; i < 4; ++i) {
        a[i] = *(const f16x8*)(Ah + kk * 4096 + (wrow + i * 16 + l16) * 32 + quad * 8);
        b[i] = *(const f16x8*)(Bh + kk * 4096 + (wcol + i * 16 + l16) * 32 + quad * 8);
      }
#pragma unroll
      for (int mi = 0; mi < 4; ++mi)
#pragma unroll
        for (int ni = 0; ni < 4; ++ni)
          acc[mi][ni] = mfmaH(a[mi], b[ni], acc[mi][ni]);
    }
    __syncthreads();
  }
#pragma unroll
  for (int mi = 0; mi < 4; ++mi)
#pragma unroll
    for (int ni = 0; ni < 4; ++ni)
#pragma unroll
      for (int r = 0; r < 4; ++r) {
        int row = wrow + mi * 16 + quad * 4 + r;
        int col = wcol + ni * 16 + l16;
        xh[(size_t)(m0 + row) * Cn + n0 + col] = f2h(acc[mi][ni][r]);
      }
}

// ---------------------------------------------------------------------------
// K2: S = (x_h + x_l) @ xh^T (2 terms) on causal 128x128 tiles; lazy softmax:
// P = exp(S - m_tile) fp16 into PACKED triangular tile storage; stats (m,l).
// (BK=32 kept: 3 planes at BK=64 would be 48 KB -> occupancy 4->3 blocks/CU.)
// ---------------------------------------------------------------------------
__global__ __launch_bounds__(256) void k2_scores(const u16* __restrict__ x_h,
                                                 const u16* __restrict__ x_l,
                                                 const u16* __restrict__ xh,
                                                 u16* __restrict__ P,
                                                 float* __restrict__ mt,
                                                 float* __restrict__ lt) {
  __shared__ __align__(16) union {
    struct { u16 Ah[4096], Al[4096], Bh[4096]; } s;
    struct { float Mrow[2][128]; float Lrow[2][128]; } e;
  } u;
  const int tid = threadIdx.x;
  const int bL = blockIdx.y;
  const int lin = blockIdx.x;
  int qt = 0;
  while ((qt + 1) * (qt + 2) / 2 <= lin) qt++;
  const int st = lin - qt * (qt + 1) / 2;
  const int t0 = qt * 128, s0 = st * 128;
  const int wave = tid >> 6, lane = tid & 63;
  const int wrow = (wave >> 1) * 64, wcol = (wave & 1) * 64;
  const int quad = lane >> 4, l16 = lane & 15;
  const int srow = tid >> 2, skc = (tid & 3) * 8;

  f32x4 acc[4][4] = {};
  const size_t aoff = ((size_t)bL * Tn + t0 + srow) * Cn + skc;
  const size_t boff = ((size_t)bL * Tn + s0 + srow) * Cn + skc;

  for (int k0 = 0; k0 < Cn; k0 += 32) {
#pragma unroll
    for (int i = 0; i < 2; ++i) {
      size_t ro = (size_t)i * 64 * Cn;
      int lo_ = i * 2048 + tid * 8;
      gld16(x_h + aoff + ro + k0, u.s.Ah + lo_);
      gld16(x_l + aoff + ro + k0, u.s.Al + lo_);
      gld16(xh + boff + ro + k0, u.s.Bh + lo_);
    }
    __syncthreads();
    f16x8 a_h[4], a_l[4], b_h[4];
#pragma unroll
    for (int i = 0; i < 4; ++i) {
      a_h[i] = *(const f16x8*)(u.s.Ah + (wrow + i * 16 + l16) * 32 + quad * 8);
      a_l[i] = *(const f16x8*)(u.s.Al + (wrow + i * 16 + l16) * 32 + quad * 8);
      b_h[i] = *(const f16x8*)(u.s.Bh + (wcol + i * 16 + l16) * 32 + quad * 8);
    }
#pragma unroll
    for (int mi = 0; mi < 4; ++mi)
#pragma unroll
      for (int ni = 0; ni < 4; ++ni) {
        acc[mi][ni] = mfmaH(a_h[mi], b_h[ni], acc[mi][ni]);
        acc[mi][ni] = mfmaH(a_l[mi], b_h[ni], acc[mi][ni]);
      }
    __syncthreads();
  }

  // ---- epilogue: mask, per-row max, exp, stats, packed-P write ----
  float rm[4][4];
#pragma unroll
  for (int mi = 0; mi < 4; ++mi)
#pragma unroll
    for (int r = 0; r < 4; ++r) {
      int row = wrow + mi * 16 + quad * 4 + r;
      float m = -1e30f;
#pragma unroll
      for (int ni = 0; ni < 4; ++ni) {
        int col = wcol + ni * 16 + l16;
        if (s0 + col >= t0 + row) acc[mi][ni][r] = -1e30f;
        m = fmaxf(m, acc[mi][ni][r]);
      }
      m = fmaxf(m, __shfl_xor(m, 1));
      m = fmaxf(m, __shfl_xor(m, 2));
      m = fmaxf(m, __shfl_xor(m, 4));
      m = fmaxf(m, __shfl_xor(m, 8));
      rm[mi][r] = m;
    }
  if (l16 == 0) {
#pragma unroll
    for (int mi = 0; mi < 4; ++mi)
#pragma unroll
      for (int r = 0; r < 4; ++r)
        u.e.Mrow[wave & 1][wrow + mi * 16 + quad * 4 + r] = rm[mi][r];
  }
  __syncthreads();
  float rs[4][4];
#pragma unroll
  for (int mi = 0; mi < 4; ++mi)
#pragma unroll
    for (int r = 0; r < 4; ++r) {
      int row = wrow + mi * 16 + quad * 4 + r;
      float m2 = fmaxf(u.e.Mrow[0][row], u.e.Mrow[1][row]);
      float s = 0.f;
#pragma unroll
      for (int ni = 0; ni < 4; ++ni) {
        int col = wcol + ni * 16 + l16;
        float p = (s0 + col < t0 + row) ? __expf(acc[mi][ni][r] - m2) : 0.0f;
        acc[mi][ni][r] = p;
        s += p;
      }
      s += __shfl_xor(s, 1);
      s += __shfl_xor(s, 2);
      s += __shfl_xor(s, 4);
      s += __shfl_xor(s, 8);
      rs[mi][r] = s;
      rm[mi][r] = m2;
    }
  if (l16 == 0) {
#pragma unroll
    for (int mi = 0; mi < 4; ++mi)
#pragma unroll
      for (int r = 0; r < 4; ++r)
        u.e.Lrow[wave & 1][wrow + mi * 16 + quad * 4 + r] = rs[mi][r];
  }
  __syncthreads();
  if ((wave & 1) == 0 && l16 == 0) {
#pragma unroll
    for (int mi = 0; mi < 4; ++mi)
#pragma unroll
      for (int r = 0; r < 4; ++r) {
        int row = wrow + mi * 16 + quad * 4 + r;
        size_t rI = (size_t)bL * Tn + t0 + row;
        mt[rI * 16 + st] = rm[mi][r];
        lt[rI * 16 + st] = u.e.Lrow[0][row] + u.e.Lrow[1][row];
      }
  }
  const size_t pbase = (size_t)(bL * NTRI + lin) * 16384;
#pragma unroll
  for (int mi = 0; mi < 4; ++mi)
#pragma unroll
    for (int ni = 0; ni < 4; ++ni)
#pragma unroll
      for (int r = 0; r < 4; ++r) {
        int row = wrow + mi * 16 + quad * 4 + r;
        int col = wcol + ni * 16 + l16;
        P[pbase + row * 128 + col] = f2h(acc[mi][ni][r]);
      }
}

// ---------------------------------------------------------------------------
// K3: per-row global max M and inverse denom Li. Row t=0 -> Li=0.
// ---------------------------------------------------------------------------
__global__ __launch_bounds__(256) void k3_stats(const float* __restrict__ mt,
                                                const float* __restrict__ lt,
                                                float* __restrict__ Mr,
                                                float* __restrict__ Li) {
  int r = blockIdx.x * 256 + threadIdx.x;
  int t = r & (Tn - 1);
  int nt = (t == 0) ? 0 : (((t - 1) >> 7) + 1);
  float M = -1e30f;
  for (int i = 0; i < nt; ++i) M = fmaxf(M, mt[(size_t)r * 16 + i]);
  float L = 0.f;
  for (int i = 0; i < nt; ++i) L += lt[(size_t)r * 16 + i] * __expf(mt[(size_t)r * 16 + i] - M);
  Mr[r] = M;
  Li[r] = (L > 0.f) ? 1.f / L : 0.f;
}

// ---------------------------------------------------------------------------
// ktr: xhT[b][c][s] = xh[b][s][c]  (fp16, 128x128 LDS tiles)
// ---------------------------------------------------------------------------
__global__ __launch_bounds__(256) void ktr(const u16* __restrict__ src,
                                           u16* __restrict__ dst) {
  __shared__ __align__(16) u16 S[128 * 136];
  const int t0 = blockIdx.x * 128, c0 = blockIdx.y * 128, b = blockIdx.z;
  const int tid = threadIdx.x;
#pragma unroll
  for (int i = 0; i < 8; ++i) {
    int chunk = tid + i * 256;
    int row = chunk >> 4, c8 = (chunk & 15) * 8;
    uint4 v = *(const uint4*)(src + ((size_t)b * Tn + t0 + row) * Cn + c0 + c8);
    *(uint4*)(S + row * 136 + c8) = v;
  }
  __syncthreads();
#pragma unroll
  for (int i = 0; i < 8; ++i) {
    int chunk = tid + i * 256;
    int crow = chunk >> 4, t8 = (chunk & 15) * 8;
    union { u16 s[8]; uint4 v; } o;
#pragma unroll
    for (int j = 0; j < 8; ++j) o.s[j] = S[(t8 + j) * 136 + crow];
    *(uint4*)(dst + ((size_t)b * Cn + c0 + crow) * Tn + t0 + t8) = o.v;
  }
}

// ---------------------------------------------------------------------------
// K4: out = -( (P*alpha) @ xh ), alpha folded into the A fragment.
// A = packed P tiles; B = xhT (k=s contig). BK=64 (two [128][32] halves).
// ---------------------------------------------------------------------------
__global__ __launch_bounds__(256) void k4_out(const u16* __restrict__ P,
                                              const u16* __restrict__ xhT,
                                              const float* __restrict__ mt,
                                              const float* __restrict__ Mr,
                                              const float* __restrict__ Li,
                                              float* __restrict__ out) {
  __shared__ __align__(16) u16 Ap[8192], Bp[8192];
  const int tid = threadIdx.x;
  const int tt = 15 - blockIdx.x;  // heavy tiles first
  const int cn = blockIdx.y, bL = blockIdx.z;
  const int t0 = tt * 128, c0 = cn * 128;
  const int wave = tid >> 6, lane = tid & 63;
  const int wrow = (wave >> 1) * 64, wcol = (wave & 1) * 64;
  const int quad = lane >> 4, l16 = lane & 15;

  f32x4 acc[4][4] = {};
  size_t rI[4]; float MrL[4], LiL[4];
#pragma unroll
  for (int mi = 0; mi < 4; ++mi) {
    rI[mi] = (size_t)bL * Tn + t0 + wrow + mi * 16 + l16;
    MrL[mi] = Mr[rI[mi]];
    LiL[mi] = Li[rI[mi]];
  }
  const size_t bbase = ((size_t)bL * Cn + c0) * Tn;

  for (int st = 0; st <= tt; ++st) {
    f16 ah[4];
#pragma unroll
    for (int mi = 0; mi < 4; ++mi)
      ah[mi] = (f16)(__expf(mt[rI[mi] * 16 + st] - MrL[mi]) * LiL[mi]);
    const size_t pbase = (size_t)(bL * NTRI + tt * (tt + 1) / 2 + st) * 16384;
#pragma unroll 1
    for (int kl = 0; kl < 128; kl += 64) {
#pragma unroll
      for (int i = 0; i < 4; ++i) {
        int chunk = i * 256 + tid;
        int kk = chunk >> 9, row = (chunk >> 2) & 127, c8 = (chunk & 3) * 8;
        gld16(P + pbase + (size_t)row * 128 + kl + kk * 32 + c8, Ap + chunk * 8);
        gld16(xhT + bbase + (size_t)row * Tn + st * 128 + kl + kk * 32 + c8, Bp + chunk * 8);
      }
      __syncthreads();
#pragma unroll
      for (int kk = 0; kk < 2; ++kk) {
        f16x8 a[4], b[4];
#pragma unroll
        for (int i = 0; i < 4; ++i) {
          a[i] = *(const f16x8*)(Ap + kk * 4096 + (wrow + i * 16 + l16) * 32 + quad * 8);
          f16x8 sv;
#pragma unroll
          for (int j = 0; j < 8; ++j) sv[j] = ah[i];
          a[i] = a[i] * sv;
          b[i] = *(const f16x8*)(Bp + kk * 4096 + (wcol + i * 16 + l16) * 32 + quad * 8);
        }
#pragma unroll
        for (int mi = 0; mi < 4; ++mi)
#pragma unroll
          for (int ni = 0; ni < 4; ++ni)
            acc[mi][ni] = mfmaH(a[mi], b[ni], acc[mi][ni]);
      }
      __syncthreads();
    }
  }
#pragma unroll
  for (int mi = 0; mi < 4; ++mi)
#pragma unroll
    for (int ni = 0; ni < 4; ++ni)
#pragma unroll
      for (int r = 0; r < 4; ++r) {
        int row = wrow + mi * 16 + quad * 4 + r;
        int col = wcol + ni * 16 + l16;
        out[((size_t)bL * Tn + t0 + row) * Cn + c0 + col] = -acc[mi][ni][r];
      }
}

// ---------------------------------------------------------------------------
extern "C" void kernel_launch(void* const* d_in, const int* in_sizes, int n_in,
                              void* d_out, int out_size, void* d_ws, size_t ws_size,
                              hipStream_t stream) {
  (void)in_sizes; (void)n_in; (void)out_size;
  const float* x = (const float*)d_in[0];
  const float* W = (const float*)d_in[1];
  float* out = (float*)d_out;

  // full-batch path needs ~140.6 MB; else fall back to 2 chunks (~71 MB)
  const size_t FULL_NEED = 3ull * Mn * Cn * 2 + (size_t)Bn * NTRI * 16384 * 2 +
                           (size_t)Cn * Cn * 2 + 2ull * Mn * 16 * 4 + 2ull * Mn * 4;
  const int nch = (ws_size >= FULL_NEED) ? 1 : 2;
  const int nb = Bn / nch;
  const size_t rowsC = (size_t)nb * Tn;       // rows per pass
  const size_t sA = rowsC * Cn * 2;           // fp16 plane bytes

  char* p = (char*)d_ws;
  u16* x_h = (u16*)p; p += sA;
  u16* xLT = (u16*)p; p += sA;                // x_l, later reused as xhT
  u16* xh  = (u16*)p; p += sA;
  u16* Pp  = (u16*)p; p += (size_t)nb * NTRI * 16384 * 2;
  u16* W_h = (u16*)p; p += (size_t)Cn * Cn * 2;
  float* mt = (float*)p; p += rowsC * 16 * 4;
  float* lt = (float*)p; p += rowsC * 16 * 4;
  float* Mr = (float*)p; p += rowsC * 4;
  float* Li = (float*)p; p += rowsC * 4;

  dim3 blk(256);
  ksplitW<<<dim3(Cn * Cn / 2048), blk, 0, stream>>>(W, W_h);
  for (int c = 0; c < nch; ++c) {
    const float* xc = x + (size_t)c * rowsC * Cn;
    float* oc = out + (size_t)c * rowsC * Cn;
    ksplitX<<<dim3((u32)(rowsC * Cn / 2048)), blk, 0, stream>>>(xc, x_h, xLT);
    k1_xh<<<dim3((u32)(rowsC / 128), Cn / 128), blk, 0, stream>>>(x_h, W_h, xh);
    k2_scores<<<dim3(NTRI, nb), blk, 0, stream>>>(x_h, xLT, xh, Pp, mt, lt);
    k3_stats<<<dim3((u32)(rowsC / 256)), blk, 0, stream>>>(mt, lt, Mr, Li);
    ktr<<<dim3(Tn / 128, Cn / 128, nb), blk, 0, stream>>>(xh, xLT);
    k4_out<<<dim3(16, Cn / 128, nb), blk, 0, stream>>>(Pp, xLT, mt, Mr, Li, oc);
  }
}